// Round 3
// baseline (57.531 us; speedup 1.0000x reference)
//
#include <hip/hip_runtime.h>
#include <math.h>

#define BATCH 64
#define NUM_TRAJ 128
#define NTOT (BATCH*NUM_TRAJ)
#define NSTEPS 255

static constexpr float DT = 0.00390625f; // 2^-8

typedef float v2f __attribute__((ext_vector_type(2)));

__device__ __forceinline__ v2f splat(float s) { return (v2f){s, s}; }

#if __has_builtin(__builtin_elementwise_fma)
__device__ __forceinline__ v2f vfma(v2f a, v2f b, v2f c) { return __builtin_elementwise_fma(a, b, c); }
#else
__device__ __forceinline__ v2f vfma(v2f a, v2f b, v2f c) { return (v2f){fmaf(a.x,b.x,c.x), fmaf(a.y,b.y,c.y)}; }
#endif

// quad_perm DPP shuffle (compile-time ctrl), float
template<int C>
__device__ __forceinline__ float qp(float x) {
    union { float f; int i; } u;
    u.f = x;
    u.i = __builtin_amdgcn_update_dpp(0, u.i, C, 0xF, 0xF, true);
    return u.f;
}
template<int C>
__device__ __forceinline__ v2f qp2(v2f x) {
    v2f r; r.x = qp<C>(x.x); r.y = qp<C>(x.y); return r;
}
// For lane (row) i, sum of the two "other" rows needed by H*rho:
// lane0,3 need rows 1+2 ; lane1,2 need rows 0+3.
__device__ __forceinline__ v2f qsum2(v2f x) { return qp2<65>(x) + qp2<190>(x); }

// 4 lanes per trajectory, one row of rho per lane; each element is a packed
// (re,im) pair -> v_pk_fma_f32. H = Omega*HX + eps*HZ (real symmetric sparse),
// C1=diag(1,1,-1,-1), C2=diag(1,-1,1,-1).
// rho' = rho + dt*(-i*comm) + (W_ij - i*u)*rho_ij
//   W_ij = dt*Gamma*d_ij + pAB_i + pAB_j - Re(u),  u = sum_i 2*pAB_i*rho_ii
__global__ __launch_bounds__(64) void traj_kernel(
    const float* __restrict__ inputs,
    const float* __restrict__ params,
    const float* __restrict__ wvec,
    const float* __restrict__ rho0,
    int rho0_cplx,
    float* __restrict__ ws)
{
    const int tid = blockIdx.x * 64 + threadIdx.x;
    const int g = tid >> 2;          // trajectory index
    const int r = tid & 3;           // row owned by this lane
    const int b = g & (BATCH - 1);

    const float Omega = inputs[b] + 1e-8f;
    const float a     = 0.5f * Omega;
    const float eps   = params[1];
    const float Gamma = params[2];
    const float eta   = params[3];
    const float sqge  = sqrtf(fmaxf(Gamma * eta, 0.0f));
    const float gdt   = Gamma * DT;

    // per-lane (row) constants
    const float s1  = (r < 2)  ? 1.0f : -1.0f;   // C1 diag
    const float s2  = (r & 1)  ? -1.0f : 1.0f;   // C2 diag
    const float dgH = (r == 0) ? eps : ((r == 3) ? -eps : 0.0f); // H diagonal
    const v2f av  = splat(a);
    const v2f e0v = splat(dgH - eps);   // comm col0 coefficient
    const v2f dgv = splat(dgH);
    const v2f e3v = splat(dgH + eps);   // comm col3 coefficient
    const float dm0 = gdt * ( s1 + s2 - 2.0f);
    const float dm1 = gdt * ( s1 - s2 - 2.0f);
    const float dm2 = gdt * (-s1 + s2 - 2.0f);
    const float dm3 = gdt * (-s1 - s2 - 2.0f);
    const bool is1 = (r == 1), is3 = (r == 3), ishi = (r >= 2);

    v2f q[4];
#pragma unroll
    for (int j = 0; j < 4; ++j) {
        const int idx = r * 4 + j;
        if (rho0_cplx) q[j] = (v2f){rho0[2 * idx], rho0[2 * idx + 1]};
        else           q[j] = (v2f){rho0[idx], 0.0f};
    }

    const float* wp = wvec + (size_t)g * (2 * NSTEPS);

    auto step = [&](float dwA, float dwB) {
        const float p0 = dwA + dwB;
        const float p1 = dwA - dwB;
        const float pown = fmaf(s1, dwA, s2 * dwB);

        // own-row column sums (for rho*H)
        const v2f u1 = q[1] + q[2];
        const v2f u0 = q[0] + q[3];
        // cross-row sums (for H*rho), quad DPP per component
        const v2f s0 = qsum2(q[0]);
        const v2f s1v = qsum2(q[1]);
        const v2f s2v = qsum2(q[2]);
        const v2f s3v = qsum2(q[3]);

        // comm = H rho - rho H, own row (packed re/im)
        const v2f c0 = vfma(e0v, q[0], av * (s0 - u1));
        const v2f c1 = vfma(dgv, q[1], av * (s1v - u0));
        const v2f c2 = vfma(dgv, q[2], av * (s2v - u0));
        const v2f c3 = vfma(e3v, q[3], av * (s3v - u1));

        // trace term u = sum_i 2*pAB_i * rho_ii : depth-2 diag select + butterfly
        const v2f d01 = is1 ? q[1] : q[0];
        const v2f d23 = is3 ? q[3] : q[2];
        const v2f d = ishi ? d23 : d01;
        const float twop = pown + pown;
        v2f z = splat(twop) * d;
        z += qp2<177>(z);   // xor 1 : quad_perm(1,0,3,2)
        z += qp2<78>(z);    // xor 2 : quad_perm(2,3,0,1)
        const float ur = z.x, ui = z.y;

        const float base = pown - ur;
        const float W0 = (base + dm0) + p0;
        const float W1 = (base + dm1) + p1;
        const float W2 = (base + dm2) - p1;
        const float W3 = (base + dm3) - p0;
        const v2f uiv = splat(ui);
        const v2f dtv = splat(DT);

        // n = x + DT*(c.y,-c.x) + W*x + ui*(x.y,-x.x)
        {
            const v2f cs = (v2f){c0.y, -c0.x};
            const v2f xs = (v2f){q[0].y, -q[0].x};
            v2f n = vfma(dtv, cs, q[0]);
            n = vfma(splat(W0), q[0], n);
            q[0] = vfma(uiv, xs, n);
        }
        {
            const v2f cs = (v2f){c1.y, -c1.x};
            const v2f xs = (v2f){q[1].y, -q[1].x};
            v2f n = vfma(dtv, cs, q[1]);
            n = vfma(splat(W1), q[1], n);
            q[1] = vfma(uiv, xs, n);
        }
        {
            const v2f cs = (v2f){c2.y, -c2.x};
            const v2f xs = (v2f){q[2].y, -q[2].x};
            v2f n = vfma(dtv, cs, q[2]);
            n = vfma(splat(W2), q[2], n);
            q[2] = vfma(uiv, xs, n);
        }
        {
            const v2f cs = (v2f){c3.y, -c3.x};
            const v2f xs = (v2f){q[3].y, -q[3].x};
            v2f n = vfma(dtv, cs, q[3]);
            n = vfma(splat(W3), q[3], n);
            q[3] = vfma(uiv, xs, n);
        }
    };

    // 63 full chunks of 4 steps + tail of 3; lane r supplies step (4*t4+r)'s
    // noise, quad-broadcast per sub-step. Next chunk's load is prefetched
    // before the current chunk's compute (software pipeline).
    float2 wl = *reinterpret_cast<const float2*>(wp + 2 * r);
    float wA = wl.x * sqge, wB = wl.y * sqge;
#pragma unroll 1
    for (int t4 = 0; t4 < 63; ++t4) {
        int nidx = 4 * (t4 + 1) + r;
        if (nidx > 254) nidx = 254;
        const float2 wn = *reinterpret_cast<const float2*>(wp + 2 * nidx);
        step(qp<0>(wA),   qp<0>(wB));    // broadcast lane 0
        step(qp<85>(wA),  qp<85>(wB));   // broadcast lane 1
        step(qp<170>(wA), qp<170>(wB));  // broadcast lane 2
        step(qp<255>(wA), qp<255>(wB));  // broadcast lane 3
        wA = wn.x * sqge; wB = wn.y * sqge;
    }
    // tail: steps 252..254
    step(qp<0>(wA),   qp<0>(wB));
    step(qp<85>(wA),  qp<85>(wB));
    step(qp<170>(wA), qp<170>(wB));

    // ws layout per trajectory: floats [0..15] = Re(rho) row-major, [16..31] = Im
    float4* o = reinterpret_cast<float4*>(ws + (size_t)g * 32);
    o[r]     = make_float4(q[0].x, q[1].x, q[2].x, q[3].x);
    o[4 + r] = make_float4(q[0].y, q[1].y, q[2].y, q[3].y);
}

__device__ inline void fill_proj(int p, float s, float pr[2][2], float pim[2][2])
{
    pr[0][0] = 0.5f; pr[0][1] = 0.f; pr[1][0] = 0.f; pr[1][1] = 0.5f;
    pim[0][0] = 0.f; pim[0][1] = 0.f; pim[1][0] = 0.f; pim[1][1] = 0.f;
    const float h = 0.5f * s;
    if (p == 0)      { pr[0][1] += h;  pr[1][0] += h; }   // sigma_x
    else if (p == 1) { pim[0][1] -= h; pim[1][0] += h; }  // sigma_y
    else             { pr[0][0] += h;  pr[1][1] -= h; }   // sigma_z
}

__device__ inline void fill_id(float pr[2][2], float pim[2][2])
{
    pr[0][0] = 1.f; pr[0][1] = 0.f; pr[1][0] = 0.f; pr[1][1] = 1.f;
    pim[0][0] = 0.f; pim[0][1] = 0.f; pim[1][0] = 0.f; pim[1][1] = 0.f;
}

// One block per batch element: reduce 128 trajectories -> rho_mean, compute 42
// measurement probabilities tr(M rho), clip, write [probs | input], then rho_mean.
__global__ __launch_bounds__(64) void reduce_meas_kernel(
    const float* __restrict__ ws,
    const float* __restrict__ inputs,
    float* __restrict__ out,
    int out_size)
{
    const int b = blockIdx.x;
    const int tid = threadIdx.x;
    __shared__ float sr[16], si[16];

    if (tid < 32) {
        const int plane = tid >> 4;
        const int e = tid & 15;
        float s = 0.f;
        for (int k = 0; k < NUM_TRAJ; k++)
            s += ws[((size_t)(k * BATCH + b)) * 32 + plane * 16 + e];
        s *= (1.0f / NUM_TRAJ);
        if (plane == 0) sr[e] = s; else si[e] = s;
    }
    __syncthreads();

    if (tid < 42) {
        float par[2][2], pai[2][2], pbr[2][2], pbi[2][2];
        const int m = tid;
        if (m < 36) {
            const int ia = m / 12, rem = m - ia * 12;
            const int ib = rem / 4, r2 = rem - ib * 4;
            fill_proj(ia, (r2 & 2) ? -1.f : 1.f, par, pai);
            fill_proj(ib, (r2 & 1) ? -1.f : 1.f, pbr, pbi);
        } else if (m < 39) {
            fill_proj(m - 36, 1.f, par, pai);
            fill_id(pbr, pbi);
        } else {
            fill_id(par, pai);
            fill_proj(m - 39, 1.f, pbr, pbi);
        }
        float prob = 0.f;
#pragma unroll
        for (int a1 = 0; a1 < 2; a1++)
#pragma unroll
            for (int b1 = 0; b1 < 2; b1++)
#pragma unroll
                for (int a2 = 0; a2 < 2; a2++)
#pragma unroll
                    for (int b2 = 0; b2 < 2; b2++) {
                        const int i = 2 * a1 + b1, j = 2 * a2 + b2;
                        const float Mr = par[a1][a2] * pbr[b1][b2] - pai[a1][a2] * pbi[b1][b2];
                        const float Mi = par[a1][a2] * pbi[b1][b2] + pai[a1][a2] * pbr[b1][b2];
                        prob += Mr * sr[j * 4 + i] - Mi * si[j * 4 + i];
                    }
        prob = fminf(fmaxf(prob, 0.f), 1.f);
        out[b * 43 + m] = prob;
    } else if (tid == 42) {
        out[b * 43 + 42] = inputs[b];
    }

    if (out_size >= 2752 + 2048) {
        if (tid < 16) {
            out[2752 + b * 32 + 2 * tid]     = sr[tid];
            out[2752 + b * 32 + 2 * tid + 1] = si[tid];
        }
    } else if (out_size >= 2752 + 1024) {
        if (tid < 16) out[2752 + b * 16 + tid] = sr[tid];
    }
}

extern "C" void kernel_launch(void* const* d_in, const int* in_sizes, int n_in,
                              void* d_out, int out_size, void* d_ws, size_t ws_size,
                              hipStream_t stream)
{
    const float* inputs = (const float*)d_in[0];
    const float* params = (const float*)d_in[1];
    const float* wvec   = (const float*)d_in[2];
    const float* rho0   = (const float*)d_in[3];
    const int rho0_cplx = (n_in > 3 && in_sizes[3] >= 32) ? 1 : 0;
    float* ws = (float*)d_ws;

    traj_kernel<<<(NTOT * 4) / 64, 64, 0, stream>>>(inputs, params, wvec, rho0, rho0_cplx, ws);
    reduce_meas_kernel<<<BATCH, 64, 0, stream>>>(ws, inputs, (float*)d_out, out_size);
}

// Round 5
// 43.449 us; speedup vs baseline: 1.3241x; 1.3241x over previous
//
#include <hip/hip_runtime.h>
#include <math.h>

#define BATCH 64
#define NUM_TRAJ 128
#define NTOT (BATCH*NUM_TRAJ)
#define NSTEPS 255

static constexpr float DT = 0.00390625f; // 2^-8

// quad_perm DPP shuffle (compile-time ctrl), float
template<int C>
__device__ __forceinline__ float qp(float x) {
    union { float f; int i; } u;
    u.f = x;
    u.i = __builtin_amdgcn_update_dpp(0, u.i, C, 0xF, 0xF, true);
    return u.f;
}
// ds_swizzle (compile-time pattern), float. bitmask mode:
// src_lane = ((lane & and) | or) ^ xor ; offset = (xor<<10)|(or<<5)|and
template<int OFF>
__device__ __forceinline__ float dsw(float x) {
    union { float f; int i; } u;
    u.f = x;
    u.i = __builtin_amdgcn_ds_swizzle(u.i, OFF);
    return u.f;
}
// For lane (row) r in a quad: sum of the two "other" rows needed by H*rho:
// rows 1+2 for r=0,3 ; rows 0+3 for r=1,2.
__device__ __forceinline__ float qsum2(float x) { return qp<65>(x) + qp<190>(x); }

// 8 lanes per trajectory: lane = c*4 + r. Row r, column-pair c: c=0 owns cols
// {0,3}, c=1 owns cols {1,2}; each element is an in-lane (re,im) float pair.
// H = Omega*HX + eps*HZ, C1=diag(1,1,-1,-1), C2=diag(1,-1,1,-1).
// rho' = rho + dt*(-i*comm) + (W_ij - i*u)*rho_ij
//   comm[r][j] = (h_r - h_j) rho_rj + a*(S_j - u_pair(j))
//   W_ij = dt*Gamma*d_ij + p_i + p_j - Re(u),  u = sum_i 2 p_i rho_ii
__global__ __launch_bounds__(64) void traj_kernel(
    const float* __restrict__ inputs,
    const float* __restrict__ params,
    const float* __restrict__ wvec,
    const float* __restrict__ rho0,
    int rho0_cplx,
    float* __restrict__ ws)
{
    const int tid = blockIdx.x * 64 + threadIdx.x;
    const int g  = tid >> 3;          // trajectory index
    const int l8 = tid & 7;           // lane within 8-lane group
    const int r  = l8 & 3;            // row
    const int c  = l8 >> 2;           // column pair: 0->{0,3}, 1->{1,2}
    const int b  = g & (BATCH - 1);

    const float Omega = inputs[b] + 1e-8f;
    const float a     = 0.5f * Omega;
    const float eps   = params[1];
    const float Gamma = params[2];
    const float eta   = params[3];
    const float sqge  = sqrtf(fmaxf(Gamma * eta, 0.0f));
    const float gdt   = Gamma * DT;

    // lane constants
    const float s1   = (r < 2) ? 1.0f : -1.0f;   // C1 diag at row r
    const float s2   = (r & 1) ? -1.0f : 1.0f;   // C2 diag at row r
    const float hr   = (r == 0) ? eps : ((r == 3) ? -eps : 0.0f);
    const int  colA  = c ? 1 : 0;
    const int  colB  = c ? 2 : 3;
    const float s2A  = c ? -1.0f : 1.0f;         // col A signs: s1=+1, s2=s2A
    const float coefA = hr - (c ? 0.0f : eps);   // h_r - h_colA
    const float coefB = hr + (c ? 0.0f : eps);   // h_r - h_colB
    const float dmA  = gdt * ( (s1 + s2 * s2A) - 2.0f);
    const float dmB  = gdt * (-(s1 + s2 * s2A) - 2.0f);
    const float pcs  = c ? -1.0f : 1.0f;         // p_colA = dwA + pcs*dwB
    // diag ownership selectors: each diagonal element lives in exactly one
    // lane; contribute 2*p_r*rho_rr once (tw already carries the factor 2).
    const float f1   = (r == colA) ? 1.0f : 0.0f;
    const float f2   = (r == colB) ? 1.0f : 0.0f;

    float qa_re, qa_im, qb_re, qb_im;
    {
        const int idxA = r * 4 + colA, idxB = r * 4 + colB;
        if (rho0_cplx) {
            qa_re = rho0[2 * idxA]; qa_im = rho0[2 * idxA + 1];
            qb_re = rho0[2 * idxB]; qb_im = rho0[2 * idxB + 1];
        } else {
            qa_re = rho0[idxA]; qa_im = 0.0f;
            qb_re = rho0[idxB]; qb_im = 0.0f;
        }
    }

    const float* wp = wvec + (size_t)g * (2 * NSTEPS);

    auto step = [&](float dwA, float dwB) {
        // rho*H pair sum + partner exchange (xor4) -- issued early
        const float u_re = qa_re + qb_re, u_im = qa_im + qb_im;
        const float up_re = dsw<0x101F>(u_re);
        const float up_im = dsw<0x101F>(u_im);

        // trace contribution (xor4 part issued early)
        const float pown = fmaf(s1, dwA, s2 * dwB);
        const float tw = pown + pown;
        const float tm_re = tw * fmaf(f1, qa_re, f2 * qb_re);
        const float tm_im = tw * fmaf(f1, qa_im, f2 * qb_im);
        const float tx_re = dsw<0x101F>(tm_re);
        const float tx_im = dsw<0x101F>(tm_im);

        // cross-row sums (quad DPP), per owned column per component
        const float SA_re = qsum2(qa_re), SA_im = qsum2(qa_im);
        const float SB_re = qsum2(qb_re), SB_im = qsum2(qb_im);

        // comm = H rho - rho H for the two owned elements
        const float cA_re = fmaf(coefA, qa_re, a * (SA_re - up_re));
        const float cA_im = fmaf(coefA, qa_im, a * (SA_im - up_im));
        const float cB_re = fmaf(coefB, qb_re, a * (SB_re - up_re));
        const float cB_im = fmaf(coefB, qb_im, a * (SB_im - up_im));

        // finish 8-lane trace reduce: xor4 (done) + xor1 + xor2
        float z_re = tm_re + tx_re, z_im = tm_im + tx_im;
        z_re += qp<177>(z_re); z_im += qp<177>(z_im);   // quad_perm(1,0,3,2)
        z_re += qp<78>(z_re);  z_im += qp<78>(z_im);    // quad_perm(2,3,0,1)
        const float ur = z_re, ui = z_im;

        const float pc   = fmaf(pcs, dwB, dwA);
        const float base = pown - ur;
        const float WA = (base + dmA) + pc;
        const float WB = (base + dmB) - pc;

        // n = x + DT*(c_im,-c_re) + W*x + ui*(x_im,-x_re)
        float n_re, n_im;
        n_re = fmaf(DT, cA_im, qa_re);  n_re = fmaf(WA, qa_re, n_re); n_re = fmaf( ui, qa_im, n_re);
        n_im = fmaf(-DT, cA_re, qa_im); n_im = fmaf(WA, qa_im, n_im); n_im = fmaf(-ui, qa_re, n_im);
        qa_re = n_re; qa_im = n_im;
        n_re = fmaf(DT, cB_im, qb_re);  n_re = fmaf(WB, qb_re, n_re); n_re = fmaf( ui, qb_im, n_re);
        n_im = fmaf(-DT, cB_re, qb_im); n_im = fmaf(WB, qb_im, n_im); n_im = fmaf(-ui, qb_re, n_im);
        qb_re = n_re; qb_im = n_im;
    };

    // 31 chunks of 8 steps + tail of 7. Lane l8 supplies step (8T+l8)'s noise;
    // broadcast within the 8-lane group via ds_swizzle; next chunk prefetched.
    float2 wl = *reinterpret_cast<const float2*>(wp + 2 * l8);
#pragma unroll 1
    for (int T = 0; T < 31; ++T) {
        int nidx = 8 * (T + 1) + l8;
        if (nidx > 254) nidx = 254;
        const float2 wn = *reinterpret_cast<const float2*>(wp + 2 * nidx);
        const float wA = wl.x * sqge, wB = wl.y * sqge;
        float bA[8], bB[8];
        bA[0] = dsw<0x18>(wA); bB[0] = dsw<0x18>(wB);
        bA[1] = dsw<0x38>(wA); bB[1] = dsw<0x38>(wB);
        bA[2] = dsw<0x58>(wA); bB[2] = dsw<0x58>(wB);
        bA[3] = dsw<0x78>(wA); bB[3] = dsw<0x78>(wB);
        bA[4] = dsw<0x98>(wA); bB[4] = dsw<0x98>(wB);
        bA[5] = dsw<0xB8>(wA); bB[5] = dsw<0xB8>(wB);
        bA[6] = dsw<0xD8>(wA); bB[6] = dsw<0xD8>(wB);
        bA[7] = dsw<0xF8>(wA); bB[7] = dsw<0xF8>(wB);
#pragma unroll
        for (int s = 0; s < 8; ++s) step(bA[s], bB[s]);
        wl = wn;
    }
    { // tail: steps 248..254 (7 steps; lane 7's clamped load unused)
        const float wA = wl.x * sqge, wB = wl.y * sqge;
        float bA[7], bB[7];
        bA[0] = dsw<0x18>(wA); bB[0] = dsw<0x18>(wB);
        bA[1] = dsw<0x38>(wA); bB[1] = dsw<0x38>(wB);
        bA[2] = dsw<0x58>(wA); bB[2] = dsw<0x58>(wB);
        bA[3] = dsw<0x78>(wA); bB[3] = dsw<0x78>(wB);
        bA[4] = dsw<0x98>(wA); bB[4] = dsw<0x98>(wB);
        bA[5] = dsw<0xB8>(wA); bB[5] = dsw<0xB8>(wB);
        bA[6] = dsw<0xD8>(wA); bB[6] = dsw<0xD8>(wB);
#pragma unroll
        for (int s = 0; s < 7; ++s) step(bA[s], bB[s]);
    }

    // ws per trajectory: 8 lanes x float4 (qa_re, qa_im, qb_re, qb_im)
    float4* o = reinterpret_cast<float4*>(ws + (size_t)g * 32);
    o[l8] = make_float4(qa_re, qa_im, qb_re, qb_im);
}

__device__ inline void fill_proj(int p, float s, float pr[2][2], float pim[2][2])
{
    pr[0][0] = 0.5f; pr[0][1] = 0.f; pr[1][0] = 0.f; pr[1][1] = 0.5f;
    pim[0][0] = 0.f; pim[0][1] = 0.f; pim[1][0] = 0.f; pim[1][1] = 0.f;
    const float h = 0.5f * s;
    if (p == 0)      { pr[0][1] += h;  pr[1][0] += h; }   // sigma_x
    else if (p == 1) { pim[0][1] -= h; pim[1][0] += h; }  // sigma_y
    else             { pr[0][0] += h;  pr[1][1] -= h; }   // sigma_z
}

__device__ inline void fill_id(float pr[2][2], float pim[2][2])
{
    pr[0][0] = 1.f; pr[0][1] = 0.f; pr[1][0] = 0.f; pr[1][1] = 1.f;
    pim[0][0] = 0.f; pim[0][1] = 0.f; pim[1][0] = 0.f; pim[1][1] = 0.f;
}

// One block per batch element: reduce 128 trajectories -> rho_mean, compute 42
// measurement probabilities tr(M rho), clip, write [probs | input], then rho_mean.
// ws element map for (i,j): c=(j==1||j==2), slot=(j==2||j==3),
//   float index = (c*4+i)*4 + slot*2 + plane
__global__ __launch_bounds__(64) void reduce_meas_kernel(
    const float* __restrict__ ws,
    const float* __restrict__ inputs,
    float* __restrict__ out,
    int out_size)
{
    const int b = blockIdx.x;
    const int tid = threadIdx.x;
    __shared__ float part[2][32];
    __shared__ float sr[16], si[16];

    {   // 64 threads: element e (32) x k-half h (2)
        const int e = tid & 31;
        const int h = tid >> 5;
        const int plane = e >> 4;       // 0 = re, 1 = im
        const int el = e & 15;
        const int i = el >> 2, j = el & 3;
        const int cc = (j == 1 || j == 2) ? 1 : 0;
        const int slot = (j == 2 || j == 3) ? 1 : 0;
        const int fidx = (cc * 4 + i) * 4 + slot * 2 + plane;
        float s = 0.f;
#pragma unroll 4
        for (int k = h * 64; k < h * 64 + 64; k++)
            s += ws[((size_t)(k * BATCH + b)) * 32 + fidx];
        part[h][e] = s;
    }
    __syncthreads();
    if (tid < 32) {
        const float s = (part[0][tid] + part[1][tid]) * (1.0f / NUM_TRAJ);
        if (tid < 16) sr[tid] = s; else si[tid - 16] = s;
    }
    __syncthreads();

    if (tid < 42) {
        float par[2][2], pai[2][2], pbr[2][2], pbi[2][2];
        const int m = tid;
        if (m < 36) {
            const int ia = m / 12, rem = m - ia * 12;
            const int ib = rem / 4, r2 = rem - ib * 4;
            fill_proj(ia, (r2 & 2) ? -1.f : 1.f, par, pai);
            fill_proj(ib, (r2 & 1) ? -1.f : 1.f, pbr, pbi);
        } else if (m < 39) {
            fill_proj(m - 36, 1.f, par, pai);
            fill_id(pbr, pbi);
        } else {
            fill_id(par, pai);
            fill_proj(m - 39, 1.f, pbr, pbi);
        }
        float prob = 0.f;
#pragma unroll
        for (int a1 = 0; a1 < 2; a1++)
#pragma unroll
            for (int b1 = 0; b1 < 2; b1++)
#pragma unroll
                for (int a2 = 0; a2 < 2; a2++)
#pragma unroll
                    for (int b2 = 0; b2 < 2; b2++) {
                        const int i = 2 * a1 + b1, j = 2 * a2 + b2;
                        const float Mr = par[a1][a2] * pbr[b1][b2] - pai[a1][a2] * pbi[b1][b2];
                        const float Mi = par[a1][a2] * pbi[b1][b2] + pai[a1][a2] * pbr[b1][b2];
                        prob += Mr * sr[j * 4 + i] - Mi * si[j * 4 + i];
                    }
        prob = fminf(fmaxf(prob, 0.f), 1.f);
        out[b * 43 + m] = prob;
    } else if (tid == 42) {
        out[b * 43 + 42] = inputs[b];
    }

    if (out_size >= 2752 + 2048) {
        if (tid < 16) {
            out[2752 + b * 32 + 2 * tid]     = sr[tid];
            out[2752 + b * 32 + 2 * tid + 1] = si[tid];
        }
    } else if (out_size >= 2752 + 1024) {
        if (tid < 16) out[2752 + b * 16 + tid] = sr[tid];
    }
}

extern "C" void kernel_launch(void* const* d_in, const int* in_sizes, int n_in,
                              void* d_out, int out_size, void* d_ws, size_t ws_size,
                              hipStream_t stream)
{
    const float* inputs = (const float*)d_in[0];
    const float* params = (const float*)d_in[1];
    const float* wvec   = (const float*)d_in[2];
    const float* rho0   = (const float*)d_in[3];
    const int rho0_cplx = (n_in > 3 && in_sizes[3] >= 32) ? 1 : 0;
    float* ws = (float*)d_ws;

    traj_kernel<<<(NTOT * 8) / 64, 64, 0, stream>>>(inputs, params, wvec, rho0, rho0_cplx, ws);
    reduce_meas_kernel<<<BATCH, 64, 0, stream>>>(ws, inputs, (float*)d_out, out_size);
}

// Round 6
// 35.795 us; speedup vs baseline: 1.6072x; 1.2138x over previous
//
#include <hip/hip_runtime.h>
#include <math.h>

#define BATCH 64
#define NUM_TRAJ 128
#define NTOT (BATCH*NUM_TRAJ)
#define NSTEPS 255

static constexpr float DT = 0.00390625f; // 2^-8

// quad_perm / row DPP shuffle (compile-time ctrl), float
template<int C>
__device__ __forceinline__ float qp(float x) {
    union { float f; int i; } u;
    u.f = x;
    u.i = __builtin_amdgcn_update_dpp(0, u.i, C, 0xF, 0xF, true);
    return u.f;
}
#define DPP_HALF_MIRROR 0x141   // lane -> lane^7 within each 8-lane group

// ds_swizzle (compile-time pattern), float. bitmask mode:
// src_lane = ((lane & and) | or) ^ xor ; offset = (xor<<10)|(or<<5)|and
template<int OFF>
__device__ __forceinline__ float dsw(float x) {
    union { float f; int i; } u;
    u.f = x;
    u.i = __builtin_amdgcn_ds_swizzle(u.i, OFF);
    return u.f;
}
// For the lane holding row r in a quad: sum of the two "other" rows needed by
// H*rho: rows 1+2 for r in {0,3}; rows 0+3 for r in {1,2}. Works for both the
// identity quad (rows p) and the mirrored quad (rows 3-p) — verified per-lane.
__device__ __forceinline__ float qsum2(float x) { return qp<65>(x) + qp<190>(x); }

// 8 lanes per trajectory, mirror layout: lanes 0-3 = (c=0, r=p); lanes 4-7 =
// (c=1, r=3-p). Column pairs: c=0 owns cols {0,3}, c=1 owns cols {1,2}; each
// element is an in-lane (re,im) float pair. Partner (r,1-c) sits at lane^7 ->
// DPP row_half_mirror (no LDS-path ops in the hot step).
// H = Omega*HX + eps*HZ, C1=diag(1,1,-1,-1), C2=diag(1,-1,1,-1).
// rho' = rho + dt*(-i*comm) + (W_ij - i*u)*rho_ij
__global__ __launch_bounds__(64) void traj_kernel(
    const float* __restrict__ inputs,
    const float* __restrict__ params,
    const float* __restrict__ wvec,
    const float* __restrict__ rho0,
    int rho0_cplx,
    float* __restrict__ ws)
{
    const int tid = blockIdx.x * 64 + threadIdx.x;
    const int g  = tid >> 3;          // trajectory index
    const int l8 = tid & 7;           // lane within 8-lane group
    const int p  = l8 & 3;            // position in quad
    const int c  = l8 >> 2;           // column pair: 0->{0,3}, 1->{1,2}
    const int r  = c ? (3 - p) : p;   // row (mirrored in upper quad)
    const int b  = g & (BATCH - 1);

    const float Omega = inputs[b] + 1e-8f;
    const float a     = 0.5f * Omega;
    const float eps   = params[1];
    const float Gamma = params[2];
    const float eta   = params[3];
    const float sqge  = sqrtf(fmaxf(Gamma * eta, 0.0f));
    const float gdt   = Gamma * DT;

    // lane constants
    const float s1   = (r < 2) ? 1.0f : -1.0f;   // C1 diag at row r
    const float s2   = (r & 1) ? -1.0f : 1.0f;   // C2 diag at row r
    const float hr   = (r == 0) ? eps : ((r == 3) ? -eps : 0.0f);
    const int  colA  = c ? 1 : 0;
    const int  colB  = c ? 2 : 3;
    const float s2A  = c ? -1.0f : 1.0f;         // col A signs: s1=+1, s2=s2A
    const float coefA = hr - (c ? 0.0f : eps);   // h_r - h_colA
    const float coefB = hr + (c ? 0.0f : eps);   // h_r - h_colB
    const float dmA  = gdt * ( (s1 + s2 * s2A) - 2.0f);
    const float dmB  = gdt * (-(s1 + s2 * s2A) - 2.0f);
    const float pcs  = c ? -1.0f : 1.0f;         // p_colA = dwA + pcs*dwB
    // diag ownership: each diagonal element lives in exactly one lane;
    // contributes 2*p_r*rho_rr once (tw carries the factor 2).
    const float f1   = (r == colA) ? 1.0f : 0.0f;
    const float f2   = (r == colB) ? 1.0f : 0.0f;

    float qa_re, qa_im, qb_re, qb_im;
    {
        const int idxA = r * 4 + colA, idxB = r * 4 + colB;
        if (rho0_cplx) {
            qa_re = rho0[2 * idxA]; qa_im = rho0[2 * idxA + 1];
            qb_re = rho0[2 * idxB]; qb_im = rho0[2 * idxB + 1];
        } else {
            qa_re = rho0[idxA]; qa_im = 0.0f;
            qb_re = rho0[idxB]; qb_im = 0.0f;
        }
    }

    const float* wp = wvec + (size_t)g * (2 * NSTEPS);

    auto step = [&](float dwA, float dwB) {
        // rho*H pair sum + partner exchange (lane^7, DPP mirror)
        const float u_re = qa_re + qb_re, u_im = qa_im + qb_im;
        const float up_re = qp<DPP_HALF_MIRROR>(u_re);
        const float up_im = qp<DPP_HALF_MIRROR>(u_im);

        // trace contribution
        const float pown = fmaf(s1, dwA, s2 * dwB);
        const float tw = pown + pown;
        const float tm_re = tw * fmaf(f1, qa_re, f2 * qb_re);
        const float tm_im = tw * fmaf(f1, qa_im, f2 * qb_im);

        // cross-row sums (quad DPP), per owned column per component
        const float SA_re = qsum2(qa_re), SA_im = qsum2(qa_im);
        const float SB_re = qsum2(qb_re), SB_im = qsum2(qb_im);

        // comm = H rho - rho H for the two owned elements
        const float cA_re = fmaf(coefA, qa_re, a * (SA_re - up_re));
        const float cA_im = fmaf(coefA, qa_im, a * (SA_im - up_im));
        const float cB_re = fmaf(coefB, qb_re, a * (SB_re - up_re));
        const float cB_im = fmaf(coefB, qb_im, a * (SB_im - up_im));

        // 8-lane trace reduce: quad xor1 + xor2, then cross-quad mirror
        float z_re = tm_re, z_im = tm_im;
        z_re += qp<177>(z_re); z_im += qp<177>(z_im);   // quad_perm(1,0,3,2)
        z_re += qp<78>(z_re);  z_im += qp<78>(z_im);    // quad_perm(2,3,0,1)
        z_re += qp<DPP_HALF_MIRROR>(z_re);
        z_im += qp<DPP_HALF_MIRROR>(z_im);
        const float ur = z_re, ui = z_im;

        const float pc   = fmaf(pcs, dwB, dwA);
        const float base = pown - ur;
        const float WA = (base + dmA) + pc;
        const float WB = (base + dmB) - pc;

        // n = x + DT*(c_im,-c_re) + W*x + ui*(x_im,-x_re)
        float n_re, n_im;
        n_re = fmaf(DT, cA_im, qa_re);  n_re = fmaf(WA, qa_re, n_re); n_re = fmaf( ui, qa_im, n_re);
        n_im = fmaf(-DT, cA_re, qa_im); n_im = fmaf(WA, qa_im, n_im); n_im = fmaf(-ui, qa_re, n_im);
        qa_re = n_re; qa_im = n_im;
        n_re = fmaf(DT, cB_im, qb_re);  n_re = fmaf(WB, qb_re, n_re); n_re = fmaf( ui, qb_im, n_re);
        n_im = fmaf(-DT, cB_re, qb_im); n_im = fmaf(WB, qb_im, n_im); n_im = fmaf(-ui, qb_re, n_im);
        qb_re = n_re; qb_im = n_im;
    };

    // 31 chunks of 8 steps + tail of 7. Lane l8 supplies step (8T+l8)'s noise;
    // broadcast within the 8-lane group via ds_swizzle; next chunk prefetched.
    float2 wl = *reinterpret_cast<const float2*>(wp + 2 * l8);
#pragma unroll 1
    for (int T = 0; T < 31; ++T) {
        int nidx = 8 * (T + 1) + l8;
        if (nidx > 254) nidx = 254;
        const float2 wn = *reinterpret_cast<const float2*>(wp + 2 * nidx);
        const float wA = wl.x * sqge, wB = wl.y * sqge;
        float bA[8], bB[8];
        bA[0] = dsw<0x18>(wA); bB[0] = dsw<0x18>(wB);
        bA[1] = dsw<0x38>(wA); bB[1] = dsw<0x38>(wB);
        bA[2] = dsw<0x58>(wA); bB[2] = dsw<0x58>(wB);
        bA[3] = dsw<0x78>(wA); bB[3] = dsw<0x78>(wB);
        bA[4] = dsw<0x98>(wA); bB[4] = dsw<0x98>(wB);
        bA[5] = dsw<0xB8>(wA); bB[5] = dsw<0xB8>(wB);
        bA[6] = dsw<0xD8>(wA); bB[6] = dsw<0xD8>(wB);
        bA[7] = dsw<0xF8>(wA); bB[7] = dsw<0xF8>(wB);
#pragma unroll
        for (int s = 0; s < 8; ++s) step(bA[s], bB[s]);
        wl = wn;
    }
    { // tail: steps 248..254 (7 steps; lane 7's clamped load unused)
        const float wA = wl.x * sqge, wB = wl.y * sqge;
        float bA[7], bB[7];
        bA[0] = dsw<0x18>(wA); bB[0] = dsw<0x18>(wB);
        bA[1] = dsw<0x38>(wA); bB[1] = dsw<0x38>(wB);
        bA[2] = dsw<0x58>(wA); bB[2] = dsw<0x58>(wB);
        bA[3] = dsw<0x78>(wA); bB[3] = dsw<0x78>(wB);
        bA[4] = dsw<0x98>(wA); bB[4] = dsw<0x98>(wB);
        bA[5] = dsw<0xB8>(wA); bB[5] = dsw<0xB8>(wB);
        bA[6] = dsw<0xD8>(wA); bB[6] = dsw<0xD8>(wB);
#pragma unroll
        for (int s = 0; s < 7; ++s) step(bA[s], bB[s]);
    }

    // ws per trajectory: slot c*4+r gets float4 (qa_re, qa_im, qb_re, qb_im)
    // (same record layout as before; upper quad writes slots in reverse order)
    float4* o = reinterpret_cast<float4*>(ws + (size_t)g * 32);
    o[c * 4 + r] = make_float4(qa_re, qa_im, qb_re, qb_im);
}

__device__ inline void fill_proj(int p, float s, float pr[2][2], float pim[2][2])
{
    pr[0][0] = 0.5f; pr[0][1] = 0.f; pr[1][0] = 0.f; pr[1][1] = 0.5f;
    pim[0][0] = 0.f; pim[0][1] = 0.f; pim[1][0] = 0.f; pim[1][1] = 0.f;
    const float h = 0.5f * s;
    if (p == 0)      { pr[0][1] += h;  pr[1][0] += h; }   // sigma_x
    else if (p == 1) { pim[0][1] -= h; pim[1][0] += h; }  // sigma_y
    else             { pr[0][0] += h;  pr[1][1] -= h; }   // sigma_z
}

__device__ inline void fill_id(float pr[2][2], float pim[2][2])
{
    pr[0][0] = 1.f; pr[0][1] = 0.f; pr[1][0] = 0.f; pr[1][1] = 1.f;
    pim[0][0] = 0.f; pim[0][1] = 0.f; pim[1][0] = 0.f; pim[1][1] = 0.f;
}

// One block per batch element: reduce 128 trajectories -> rho_mean, compute 42
// measurement probabilities tr(M rho), clip, write [probs | input], then rho_mean.
// ws element map for (i,j): c=(j==1||j==2), slot=(j==2||j==3),
//   float index = (c*4+i)*4 + slot*2 + plane
__global__ __launch_bounds__(256) void reduce_meas_kernel(
    const float* __restrict__ ws,
    const float* __restrict__ inputs,
    float* __restrict__ out,
    int out_size)
{
    const int b = blockIdx.x;
    const int tid = threadIdx.x;
    __shared__ float part[8][32];
    __shared__ float sr[16], si[16];

    {   // 256 threads: element e (32) x k-eighth h (8)
        const int e = tid & 31;
        const int h = tid >> 5;
        const int plane = e >> 4;       // 0 = re, 1 = im
        const int el = e & 15;
        const int i = el >> 2, j = el & 3;
        const int cc = (j == 1 || j == 2) ? 1 : 0;
        const int slot = (j == 2 || j == 3) ? 1 : 0;
        const int fidx = (cc * 4 + i) * 4 + slot * 2 + plane;
        float s = 0.f;
#pragma unroll 4
        for (int k = h * 16; k < h * 16 + 16; k++)
            s += ws[((size_t)(k * BATCH + b)) * 32 + fidx];
        part[h][e] = s;
    }
    __syncthreads();
    if (tid < 32) {
        float s = 0.f;
#pragma unroll
        for (int h = 0; h < 8; h++) s += part[h][tid];
        s *= (1.0f / NUM_TRAJ);
        if (tid < 16) sr[tid] = s; else si[tid - 16] = s;
    }
    __syncthreads();

    if (tid < 42) {
        float par[2][2], pai[2][2], pbr[2][2], pbi[2][2];
        const int m = tid;
        if (m < 36) {
            const int ia = m / 12, rem = m - ia * 12;
            const int ib = rem / 4, r2 = rem - ib * 4;
            fill_proj(ia, (r2 & 2) ? -1.f : 1.f, par, pai);
            fill_proj(ib, (r2 & 1) ? -1.f : 1.f, pbr, pbi);
        } else if (m < 39) {
            fill_proj(m - 36, 1.f, par, pai);
            fill_id(pbr, pbi);
        } else {
            fill_id(par, pai);
            fill_proj(m - 39, 1.f, pbr, pbi);
        }
        float prob = 0.f;
#pragma unroll
        for (int a1 = 0; a1 < 2; a1++)
#pragma unroll
            for (int b1 = 0; b1 < 2; b1++)
#pragma unroll
                for (int a2 = 0; a2 < 2; a2++)
#pragma unroll
                    for (int b2 = 0; b2 < 2; b2++) {
                        const int i = 2 * a1 + b1, j = 2 * a2 + b2;
                        const float Mr = par[a1][a2] * pbr[b1][b2] - pai[a1][a2] * pbi[b1][b2];
                        const float Mi = par[a1][a2] * pbi[b1][b2] + pai[a1][a2] * pbr[b1][b2];
                        prob += Mr * sr[j * 4 + i] - Mi * si[j * 4 + i];
                    }
        prob = fminf(fmaxf(prob, 0.f), 1.f);
        out[b * 43 + m] = prob;
    } else if (tid == 42) {
        out[b * 43 + 42] = inputs[b];
    }

    if (out_size >= 2752 + 2048) {
        if (tid < 16) {
            out[2752 + b * 32 + 2 * tid]     = sr[tid];
            out[2752 + b * 32 + 2 * tid + 1] = si[tid];
        }
    } else if (out_size >= 2752 + 1024) {
        if (tid < 16) out[2752 + b * 16 + tid] = sr[tid];
    }
}

extern "C" void kernel_launch(void* const* d_in, const int* in_sizes, int n_in,
                              void* d_out, int out_size, void* d_ws, size_t ws_size,
                              hipStream_t stream)
{
    const float* inputs = (const float*)d_in[0];
    const float* params = (const float*)d_in[1];
    const float* wvec   = (const float*)d_in[2];
    const float* rho0   = (const float*)d_in[3];
    const int rho0_cplx = (n_in > 3 && in_sizes[3] >= 32) ? 1 : 0;
    float* ws = (float*)d_ws;

    traj_kernel<<<(NTOT * 8) / 64, 64, 0, stream>>>(inputs, params, wvec, rho0, rho0_cplx, ws);
    reduce_meas_kernel<<<BATCH, 256, 0, stream>>>(ws, inputs, (float*)d_out, out_size);
}